// Round 5
// baseline (118.673 us; speedup 1.0000x reference)
//
#include <hip/hip_runtime.h>

#define WST 72   // f16 LDS row stride (144 B = 9*16: aligned, benign banks)
#define LOG2E 1.44269504f

typedef __attribute__((ext_vector_type(4))) float    f32x4;
typedef __attribute__((ext_vector_type(2))) float    f32x2;
typedef __attribute__((ext_vector_type(8))) _Float16 f16x8;
typedef __attribute__((ext_vector_type(2))) _Float16 f16x2;
typedef __attribute__((ext_vector_type(2))) __fp16   fp16x2_raw;

union U8 { f16x8 v; f16x2 h[4]; };

__device__ __forceinline__ float rcp_f(float x) { return __builtin_amdgcn_rcpf(x); }
__device__ __forceinline__ float exp2_f(float x) { return __builtin_amdgcn_exp2f(x); }
__device__ __forceinline__ float fast_sigmoid(float x) {
    return rcp_f(1.0f + __expf(-x));
}
__device__ __forceinline__ float tanh_exp(float x) {
    return 1.0f - 2.0f * rcp_f(__expf(2.0f * x) + 1.0f);
}
__device__ __forceinline__ f16x2 pkrtz(float a, float b) {
    fp16x2_raw r = __builtin_amdgcn_cvt_pkrtz(a, b);
    return __builtin_bit_cast(f16x2, r);
}

// ---- weight staging: global f32 -> LDS f16 transposed (Wt[c*WST+k] = W[k][c])
// 512 threads, 8 elems each; each thread stays on one column c = tid&63.
__device__ __forceinline__ void stage_w(const float* __restrict__ W, _Float16* Wt,
                                        int tid, float scale, float* csbuf) {
    float v[8];
#pragma unroll
    for (int i = 0; i < 8; ++i) v[i] = W[tid + i * 512];
    float cs = 0.0f;
#pragma unroll
    for (int i = 0; i < 8; ++i) {
        int idx = tid + i * 512;
        _Float16 hv = (_Float16)(v[i] * scale);
        Wt[(idx & 63) * WST + (idx >> 6)] = hv;
        cs += (float)hv;
    }
    if (csbuf) csbuf[(tid >> 6) * 64 + (tid & 63)] = cs;
}

// one 16x16(x64) strip of a GEMM: wave covers 16 A-rows, cols [colb, +16) and
// [colb+16, +32). acc pre-loaded with bias.
__device__ __forceinline__ void gemm2(const _Float16* Act, int arow, int qd,
                                      const _Float16* Wt, int colb,
                                      f32x4 acc[2]) {
    f16x8 a0 = *(const f16x8*)(Act + arow * WST + qd * 8);
    f16x8 a1 = *(const f16x8*)(Act + arow * WST + 32 + qd * 8);
#pragma unroll
    for (int cc = 0; cc < 2; ++cc) {
        const _Float16* wr = Wt + (colb + cc * 16) * WST + qd * 8;
        f16x8 b0 = *(const f16x8*)(wr);
        f16x8 b1 = *(const f16x8*)(wr + 32);
        acc[cc] = __builtin_amdgcn_mfma_f32_16x16x32_f16(a0, b0, acc[cc], 0, 0, 0);
        acc[cc] = __builtin_amdgcn_mfma_f32_16x16x32_f16(a1, b1, acc[cc], 0, 0, 0);
    }
}

// ---------------------------------------------------------------------------
// fused_all: block = (n, j-quarter: 16 j-rows), grid 512, 512 thr, LDS 78.3 KB
// => 2 blocks/CU, 4 waves/SIMD (launch_bounds(512,4), VGPR<=128). Binary-loop
// B-fragments are re-read from LDS per iteration (register diet); co-resident
// block hides prep-phase latency. Exclusive j-ownership => plain stores.
// ---------------------------------------------------------------------------
__global__ __launch_bounds__(512, 4) void fused_all_kernel(
    const float* __restrict__ x,
    const float* __restrict__ W_lin, const float* __restrict__ b_lin,
    const float* __restrict__ Wu1,  const float* __restrict__ bu1,
    const float* __restrict__ Wu2,  const float* __restrict__ bu2,
    const float* __restrict__ Wug1, const float* __restrict__ bug1,
    const float* __restrict__ Wug2, const float* __restrict__ bug2,
    const float* __restrict__ Wb1,  const float* __restrict__ bb1,
    const float* __restrict__ Wb2,  const float* __restrict__ bb2,
    const float* __restrict__ Wbg1, const float* __restrict__ bbg1,
    const float* __restrict__ Wbg2, const float* __restrict__ bbg2,
    float* __restrict__ out)
{
    // Slot rotation:
    //  A: x(f16) -> Wb1P -> Wbg1P -> Wug1 -> Wug2 -> 2log2e*Wbg2 (binary bwg)
    //  B: W_lin  -> Tu(rows 0-15) / Tg(rows 16-31)
    //  C: Wb1Q -> Wbg1Q -> Wu1 -> Wu2 -> -2*Wb2 (binary bwm)
    //  SH: h(64xWST); after P5 dead -> um / csm / csg
    __shared__ __align__(16) char smem[78336];
    _Float16* A  = (_Float16*)(smem);              // 9216
    _Float16* B  = (_Float16*)(smem + 9216);       // 9216
    _Float16* C  = (_Float16*)(smem + 18432);      // 9216
    _Float16* SH = (_Float16*)(smem + 27648);      // 9216
    float*    um  = (float*)(smem + 27648);        // 16x64 f32 (4096)  [post-P5]
    float*    csm = (float*)(smem + 31744);        // 8x64 f32 (2048)
    float*    csg = (float*)(smem + 33792);        // 8x64 f32 (2048)
    float*    EQb  = (float*)(smem + 36864);       // 64x64 f32 (16384)
    float*    EQgb = (float*)(smem + 53248);       // 64x64 f32 (16384)
    float*    EPm  = (float*)(smem + 69632);       // 16x68 f32 (4352)
    float*    EPgm = (float*)(smem + 73984);       // 16x68 f32 (4352)
    float*    Red  = (float*)(smem + 36864);       // 32768 alias EQb+EQgb (post-loop)

    int tid = threadIdx.x, w = tid >> 6, l = tid & 63;
    int qd = l >> 4, l16 = l & 15;
    int n = blockIdx.x >> 2, jq = blockIdx.x & 3;

    // full 64x64 gemm mapping (h, EQ, EQg): 4 row-quarters x 2 col-halves
    int rw = w & 3, ch = w >> 2;
    int arow = rw * 16 + l16;
    int colb = ch * 32 + l16;
    int crow = rw * 16 + qd * 4;

    // 16-row strip mapping (EP/EPg/Tu/Tg/U/G): wave pair covers 16x64
    int wp = w & 1;
    int colb16 = wp * 32 + l16;
    bool g01 = (w < 2), g23 = (w >= 2) && (w < 4);   // wave-uniform

    f32x4 acc[2];

    // ---- P0: stage x -> A (f16, [row][c]), W_lin -> B ----
#pragma unroll
    for (int i = 0; i < 4; ++i) {
        int e = tid * 2 + i * 1024;
        f32x2 v = *(const f32x2*)(x + (size_t)n * 4096 + e);
        f16x2 p; p[0] = (_Float16)v[0]; p[1] = (_Float16)v[1];
        *(f16x2*)(A + (e >> 6) * WST + (e & 63)) = p;
    }
    stage_w(W_lin, B, tid, 1.0f, nullptr);
    __syncthreads();

    // ---- P1: h = x@W_lin + b_lin -> SH (all 8 waves); stage Wb1Q -> C ----
#pragma unroll
    for (int cc = 0; cc < 2; ++cc) {
        float bv = b_lin[colb + cc * 16];
        acc[cc] = (f32x4){bv, bv, bv, bv};
    }
    gemm2(A, arow, qd, B, colb, acc);
#pragma unroll
    for (int cc = 0; cc < 2; ++cc)
#pragma unroll
        for (int r = 0; r < 4; ++r)
            SH[(crow + r) * WST + colb + cc * 16] = (_Float16)acc[cc][r];
    stage_w(Wb1 + 4096, C, tid, 1.0f, nullptr);
    __syncthreads();

    // ---- P2: EQ = exp(2(h@Wb1Q)) -> EQb (all waves); stage Wb1P -> A ----
    acc[0] = (f32x4){0.f, 0.f, 0.f, 0.f};
    acc[1] = (f32x4){0.f, 0.f, 0.f, 0.f};
    gemm2(SH, arow, qd, C, colb, acc);
#pragma unroll
    for (int cc = 0; cc < 2; ++cc)
#pragma unroll
        for (int r = 0; r < 4; ++r)
            EQb[(crow + r) * 64 + colb + cc * 16] = __expf(2.0f * acc[cc][r]);
    stage_w(Wb1, A, tid, 1.0f, nullptr);
    __syncthreads();

    // ---- P3: EP = exp(2(h_j@Wb1P+bb1)) -> EPm (waves 0-1); stage Wbg1Q -> C ----
    if (g01) {
#pragma unroll
        for (int cc = 0; cc < 2; ++cc) {
            float bv = bb1[colb16 + cc * 16];
            acc[cc] = (f32x4){bv, bv, bv, bv};
        }
        gemm2(SH, jq * 16 + l16, qd, A, colb16, acc);
#pragma unroll
        for (int cc = 0; cc < 2; ++cc)
#pragma unroll
            for (int r = 0; r < 4; ++r)
                EPm[(qd * 4 + r) * 68 + colb16 + cc * 16] = __expf(2.0f * acc[cc][r]);
    }
    stage_w(Wbg1 + 4096, C, tid, 1.0f, nullptr);
    __syncthreads();

    // ---- P4: EQg = exp(2(h@Wbg1Q)) -> EQgb (all waves); stage Wbg1P -> A ----
    acc[0] = (f32x4){0.f, 0.f, 0.f, 0.f};
    acc[1] = (f32x4){0.f, 0.f, 0.f, 0.f};
    gemm2(SH, arow, qd, C, colb, acc);
#pragma unroll
    for (int cc = 0; cc < 2; ++cc)
#pragma unroll
        for (int r = 0; r < 4; ++r)
            EQgb[(crow + r) * 64 + colb + cc * 16] = __expf(2.0f * acc[cc][r]);
    stage_w(Wbg1, A, tid, 1.0f, nullptr);
    __syncthreads();

    // ---- P5: EPg -> EPgm (waves 2-3); stage Wu1 -> C ----
    if (g23) {
#pragma unroll
        for (int cc = 0; cc < 2; ++cc) {
            float bv = bbg1[colb16 + cc * 16];
            acc[cc] = (f32x4){bv, bv, bv, bv};
        }
        gemm2(SH, jq * 16 + l16, qd, A, colb16, acc);
#pragma unroll
        for (int cc = 0; cc < 2; ++cc)
#pragma unroll
            for (int r = 0; r < 4; ++r)
                EPgm[(qd * 4 + r) * 68 + colb16 + cc * 16] = __expf(2.0f * acc[cc][r]);
    }
    stage_w(Wu1, C, tid, 1.0f, nullptr);
    __syncthreads();

    // ---- P6: Tu = tanh(h_j@Wu1+bu1) -> B rows 0-15 (waves 0-1); stage Wug1 -> A ----
    if (g01) {
#pragma unroll
        for (int cc = 0; cc < 2; ++cc) {
            float bv = bu1[colb16 + cc * 16];
            acc[cc] = (f32x4){bv, bv, bv, bv};
        }
        gemm2(SH, jq * 16 + l16, qd, C, colb16, acc);
#pragma unroll
        for (int cc = 0; cc < 2; ++cc)
#pragma unroll
            for (int r = 0; r < 4; ++r)
                B[(qd * 4 + r) * WST + colb16 + cc * 16] = (_Float16)tanh_exp(acc[cc][r]);
    }
    stage_w(Wug1, A, tid, 1.0f, nullptr);
    __syncthreads();

    // ---- P7: Tg = tanh(h_j@Wug1+bug1) -> B rows 16-31 (waves 2-3); stage Wu2 -> C ----
    if (g23) {
#pragma unroll
        for (int cc = 0; cc < 2; ++cc) {
            float bv = bug1[colb16 + cc * 16];
            acc[cc] = (f32x4){bv, bv, bv, bv};
        }
        gemm2(SH, jq * 16 + l16, qd, A, colb16, acc);
#pragma unroll
        for (int cc = 0; cc < 2; ++cc)
#pragma unroll
            for (int r = 0; r < 4; ++r)
                B[(16 + qd * 4 + r) * WST + colb16 + cc * 16] = (_Float16)tanh_exp(acc[cc][r]);
    }
    stage_w(Wu2, C, tid, 1.0f, nullptr);
    __syncthreads();

    // ---- P8: U = Tu@Wu2 + bu2 -> regs (waves 0-1); stage Wug2 -> A ----
    f32x4 ua[2];
    if (g01) {
#pragma unroll
        for (int cc = 0; cc < 2; ++cc) {
            float bv = bu2[colb16 + cc * 16];
            ua[cc] = (f32x4){bv, bv, bv, bv};
        }
        gemm2(B, l16, qd, C, colb16, ua);
    }
    stage_w(Wug2, A, tid, 1.0f, nullptr);
    __syncthreads();

    // ---- P9: G = Tg@Wug2 + bug2 -> regs (waves 0-1); stage -2*Wb2 -> C (+csm) ----
    f32x4 ga[2];
    if (g01) {
#pragma unroll
        for (int cc = 0; cc < 2; ++cc) {
            float bv = bug2[colb16 + cc * 16];
            ga[cc] = (f32x4){bv, bv, bv, bv};
        }
        gemm2(B, 16 + l16, qd, A, colb16, ga);
    }
    stage_w(Wb2, C, tid, -2.0f, csm);
    __syncthreads();

    // ---- P10: um = U*sigmoid(G) -> um LDS (waves 0-1);
    //           stage 2log2e*Wbg2 -> A (+csg) ----
    if (g01) {
#pragma unroll
        for (int cc = 0; cc < 2; ++cc)
#pragma unroll
            for (int r = 0; r < 4; ++r)
                um[(qd * 4 + r) * 64 + colb16 + cc * 16] =
                    ua[cc][r] * fast_sigmoid(ga[cc][r]);
    }
    stage_w(Wbg2, A, tid, 2.0f * LOG2E, csg);
    __syncthreads();

    // =============== binary phase: wave w = i-range, 8 ii each ===============
    float bim[4], big[4];
#pragma unroll
    for (int cc = 0; cc < 4; ++cc) {
        int c = cc * 16 + l16;
        float sm = 0.0f, sg = 0.0f;
#pragma unroll
        for (int m = 0; m < 8; ++m) {
            sm += csm[m * 64 + c];
            sg += csg[m * 64 + c];
        }
        bim[cc] = bb2[c] - 0.5f * sm;
        big[cc] = -LOG2E * bbg2[c] - 0.5f * sg;
    }

    // P fragments (loop-invariant, register-resident; lane l16 = local j-row)
    const float* pr  = EPm  + l16 * 68;
    const float* pgr = EPgm + l16 * 68;
    f32x4 pm[4], pg[4];
    pm[0] = *(const f32x4*)(pr + qd * 8);
    pm[1] = *(const f32x4*)(pr + qd * 8 + 4);
    pm[2] = *(const f32x4*)(pr + 32 + qd * 8);
    pm[3] = *(const f32x4*)(pr + 32 + qd * 8 + 4);
    pg[0] = *(const f32x4*)(pgr + qd * 8);
    pg[1] = *(const f32x4*)(pgr + qd * 8 + 4);
    pg[2] = *(const f32x4*)(pgr + 32 + qd * 8);
    pg[3] = *(const f32x4*)(pgr + 32 + qd * 8 + 4);

    f32x4 bacc[4];
#pragma unroll
    for (int cc = 0; cc < 4; ++cc) bacc[cc] = (f32x4){0.f, 0.f, 0.f, 0.f};

#pragma unroll 2
    for (int ii = w * 8; ii < w * 8 + 8; ++ii) {
        // keep loop-invariant B-frag LDS reads INSIDE the loop (register diet
        // for the 128-VGPR / 4-waves-per-SIMD cap): block LICM hoisting.
        asm volatile("" ::: "memory");
        const float* qm = EQb  + ii * 64;
        const float* qg = EQgb + ii * 64;
        U8 am[2], ag[2];
#pragma unroll
        for (int kk = 0; kk < 2; ++kk) {
            int cb = kk * 32 + qd * 8;
            f32x4 qa = *(const f32x4*)(qm + cb);
            f32x4 qb = *(const f32x4*)(qm + cb + 4);
            f32x4 ha = *(const f32x4*)(qg + cb);
            f32x4 hb = *(const f32x4*)(qg + cb + 4);
#pragma unroll
            for (int t = 0; t < 2; ++t) {
                float a0 = __builtin_fmaf(pm[kk*2][2*t],   qa[2*t],   1.0f);
                float a1 = __builtin_fmaf(pm[kk*2][2*t+1], qa[2*t+1], 1.0f);
                float ri = rcp_f(a0 * a1);
                am[kk].h[t]     = pkrtz(ri * a1, ri * a0);
                float b0f = __builtin_fmaf(pm[kk*2+1][2*t],   qb[2*t],   1.0f);
                float b1f = __builtin_fmaf(pm[kk*2+1][2*t+1], qb[2*t+1], 1.0f);
                float rj = rcp_f(b0f * b1f);
                am[kk].h[2 + t] = pkrtz(rj * b1f, rj * b0f);
                float c0 = __builtin_fmaf(pg[kk*2][2*t],   ha[2*t],   1.0f);
                float c1 = __builtin_fmaf(pg[kk*2][2*t+1], ha[2*t+1], 1.0f);
                float rk = rcp_f(c0 * c1);
                ag[kk].h[t]     = pkrtz(rk * c1, rk * c0);
                float d0 = __builtin_fmaf(pg[kk*2+1][2*t],   hb[2*t],   1.0f);
                float d1 = __builtin_fmaf(pg[kk*2+1][2*t+1], hb[2*t+1], 1.0f);
                float rl = rcp_f(d0 * d1);
                ag[kk].h[2 + t] = pkrtz(rl * d1, rl * d0);
            }
        }
#pragma unroll
        for (int cc = 0; cc < 4; ++cc) {
            const _Float16* wm = C + (cc * 16 + l16) * WST + qd * 8;
            const _Float16* wg = A + (cc * 16 + l16) * WST + qd * 8;
            f16x8 bm0 = *(const f16x8*)(wm);
            f16x8 bm1 = *(const f16x8*)(wm + 32);
            f16x8 bg0 = *(const f16x8*)(wg);
            f16x8 bg1 = *(const f16x8*)(wg + 32);
            f32x4 d = {bim[cc], bim[cc], bim[cc], bim[cc]};
            d = __builtin_amdgcn_mfma_f32_16x16x32_f16(am[0].v, bm0, d, 0, 0, 0);
            d = __builtin_amdgcn_mfma_f32_16x16x32_f16(am[1].v, bm1, d, 0, 0, 0);
            f32x4 e = {big[cc], big[cc], big[cc], big[cc]};
            e = __builtin_amdgcn_mfma_f32_16x16x32_f16(ag[0].v, bg0, e, 0, 0, 0);
            e = __builtin_amdgcn_mfma_f32_16x16x32_f16(ag[1].v, bg1, e, 0, 0, 0);
            float v0 = exp2_f(e[0]), v1 = exp2_f(e[1]);
            float u0 = 1.0f + v0, u1 = 1.0f + v1;
            float r01 = rcp_f(u0 * u1);
            bacc[cc][0] = __builtin_fmaf(d[0] * u1, r01, bacc[cc][0]);
            bacc[cc][1] = __builtin_fmaf(d[1] * u0, r01, bacc[cc][1]);
            float v2 = exp2_f(e[2]), v3 = exp2_f(e[3]);
            float u2 = 1.0f + v2, u3 = 1.0f + v3;
            float r23 = rcp_f(u2 * u3);
            bacc[cc][2] = __builtin_fmaf(d[2] * u3, r23, bacc[cc][2]);
            bacc[cc][3] = __builtin_fmaf(d[3] * u2, r23, bacc[cc][3]);
        }
    }

    __syncthreads();   // all waves done reading EQb/EQgb before Red overwrites
#pragma unroll
    for (int cc = 0; cc < 4; ++cc)
#pragma unroll
        for (int r = 0; r < 4; ++r)
            Red[w * 1024 + (qd * 4 + r) * 64 + cc * 16 + l16] = bacc[cc][r];
    __syncthreads();

    // reduce 8 i-ranges, add unary, write out (512 thr x 2 f32 = 16x64)
    {
        int e = tid * 2;
        int lr = e >> 6, col = e & 63;
        f32x2 s = {0.f, 0.f};
#pragma unroll
        for (int p = 0; p < 8; ++p)
            s += *(const f32x2*)(Red + p * 1024 + lr * 64 + col);
        f32x2 u = *(const f32x2*)(um + lr * 64 + col);
        f32x2 o;
        o[0] = u[0] + s[0] * (1.0f / 63.0f);
        o[1] = u[1] + s[1] * (1.0f / 63.0f);
        *(f32x2*)(out + (size_t)n * 4096 + (size_t)(jq * 16 + lr) * 64 + col) = o;
    }
}

extern "C" void kernel_launch(void* const* d_in, const int* in_sizes, int n_in,
                              void* d_out, int out_size, void* d_ws, size_t ws_size,
                              hipStream_t stream)
{
    (void)in_sizes; (void)n_in; (void)out_size; (void)d_ws; (void)ws_size;
    const float* x     = (const float*)d_in[0];
    const float* W_lin = (const float*)d_in[1];
    const float* b_lin = (const float*)d_in[2];
    const float* Wu1   = (const float*)d_in[3];
    const float* bu1   = (const float*)d_in[4];
    const float* Wu2   = (const float*)d_in[5];
    const float* bu2   = (const float*)d_in[6];
    const float* Wug1  = (const float*)d_in[7];
    const float* bug1  = (const float*)d_in[8];
    const float* Wug2  = (const float*)d_in[9];
    const float* bug2  = (const float*)d_in[10];
    const float* Wb1   = (const float*)d_in[11];
    const float* bb1   = (const float*)d_in[12];
    const float* Wb2   = (const float*)d_in[13];
    const float* bb2   = (const float*)d_in[14];
    const float* Wbg1  = (const float*)d_in[15];
    const float* bbg1  = (const float*)d_in[16];
    const float* Wbg2  = (const float*)d_in[17];
    const float* bbg2  = (const float*)d_in[18];

    hipLaunchKernelGGL(fused_all_kernel, dim3(512), dim3(512), 0, stream,
        x, W_lin, b_lin, Wu1, bu1, Wu2, bu2, Wug1, bug1, Wug2, bug2,
        Wb1, bb1, Wb2, bb2, Wbg1, bbg1, Wbg2, bbg2,
        (float*)d_out);
}